// Round 8
// baseline (44.284 us; speedup 1.0000x reference)
//
#include <hip/hip_runtime.h>

// N = 16,777,216 fp32 probabilities + int32 {0,1} targets.
//   count      = #{ p > 0.5 && t == 0 }
//   out        = mean( -(t*log p + (1-t)*log(1-p)) ) * (1 + 0.1*count)
//
// R1-R3: 79/65/62 us — plateau was f64 atomicAdd (CAS retry loop).
// R4:    disjoint partials + tiny 2nd kernel, no atomics: 30.9 us.
// R5:    fused with __threadfence: 96 us — device-scope release fence emits
//        buffer_wbl2 (whole-L2 writeback) per block x2048. Never fence
//        per-block on gfx950.
// R6:    + nontemporal loads: 28.0 us. ~6.1 TB/s read phase (~floor).
// R7:    float2-packed partials: 34.4 us — but fill-kernel calibration shows
//        the whole run was slower; noise band is +/-3-6 us. Only structural
//        changes are measurable.
// R8:    fuse final reduction WITHOUT fences: publish partials as RELAXED
//        agent-scope atomic stores (plain global_store sc1, write-through to
//        coherence point, no wbl2), order against the ticket with inline
//        s_waitcnt vmcnt(0), RELAXED agent-scope fetch_add ticket (single HW
//        atomic), last block reads partials via sc1 atomic loads. Removes
//        the 2nd kernel dispatch + its runtime.

#define N_ELEM  16777216
#define N_VEC4  (N_ELEM / 4)       // 4,194,304
#define BLOCKS  2048
#define TPB     256
#define NTHREAD (BLOCKS * TPB)     // 524,288
#define NITER   (N_VEC4 / NTHREAD) // exactly 8

typedef float f4v __attribute__((ext_vector_type(4)));
typedef int   i4v __attribute__((ext_vector_type(4)));

// d_ws layout:
//   [0     .. 16384) u64 part[2048]  { lo32 = fp32 loss-sum bits, hi32 = count }
//   [16384 .. 16388) u32 ticket counter (memset to 0 each call)
#define WS_CTR_OFF 16384

__global__ __launch_bounds__(TPB, 4) void cl_fused(
    const f4v* __restrict__ p4,
    const i4v* __restrict__ t4,
    unsigned long long* __restrict__ part,
    unsigned int*       __restrict__ ctr,
    float*              __restrict__ out)
{
    const int tid = blockIdx.x * TPB + threadIdx.x;

    f4v p[NITER];
    i4v t[NITER];
    #pragma unroll
    for (int j = 0; j < NITER; ++j) {
        p[j] = __builtin_nontemporal_load(&p4[tid + j * NTHREAD]);
        t[j] = __builtin_nontemporal_load(&t4[tid + j * NTHREAD]);
    }
    __builtin_amdgcn_sched_barrier(0);

    float        lsum = 0.0f;
    unsigned int lcnt = 0u;
    #pragma unroll
    for (int j = 0; j < NITER; ++j) {
        lsum += __logf(t[j][0] ? p[j][0] : 1.0f - p[j][0]);
        lsum += __logf(t[j][1] ? p[j][1] : 1.0f - p[j][1]);
        lsum += __logf(t[j][2] ? p[j][2] : 1.0f - p[j][2]);
        lsum += __logf(t[j][3] ? p[j][3] : 1.0f - p[j][3]);
        lcnt += (unsigned int)((p[j][0] > 0.5f) & (t[j][0] == 0));
        lcnt += (unsigned int)((p[j][1] > 0.5f) & (t[j][1] == 0));
        lcnt += (unsigned int)((p[j][2] > 0.5f) & (t[j][2] == 0));
        lcnt += (unsigned int)((p[j][3] > 0.5f) & (t[j][3] == 0));
    }
    lsum = -lsum;

    // 64-lane wave reduction
    #pragma unroll
    for (int off = 32; off > 0; off >>= 1) {
        lsum += __shfl_down(lsum, off);
        lcnt += __shfl_down(lcnt, off);
    }

    // block reduction across 4 waves
    __shared__ float        s_sum[4];
    __shared__ unsigned int s_cnt[4];
    __shared__ unsigned int s_ticket;
    const int wave = threadIdx.x >> 6;
    const int lane = threadIdx.x & 63;
    if (lane == 0) { s_sum[wave] = lsum; s_cnt[wave] = lcnt; }
    __syncthreads();

    if (threadIdx.x == 0) {
        const float        bs = s_sum[0] + s_sum[1] + s_sum[2] + s_sum[3];
        const unsigned int bc = s_cnt[0] + s_cnt[1] + s_cnt[2] + s_cnt[3];
        const unsigned long long pk =
            ((unsigned long long)bc << 32) | (unsigned long long)__float_as_uint(bs);
        // relaxed agent-scope atomic store -> global_store_dwordx2 sc1:
        // write-through to device coherence point, NO cache maintenance ops.
        __hip_atomic_store(&part[blockIdx.x], pk,
                           __ATOMIC_RELAXED, __HIP_MEMORY_SCOPE_AGENT);
        // hand-rolled release ordering: store acknowledged at coherence point
        // before the ticket increment becomes visible.
        asm volatile("s_waitcnt vmcnt(0)" ::: "memory");
        s_ticket = __hip_atomic_fetch_add(ctr, 1u,
                                          __ATOMIC_RELAXED, __HIP_MEMORY_SCOPE_AGENT);
    }
    __syncthreads();

    if (s_ticket == BLOCKS - 1) {
        // Last-arriving block: all 2048 partials are at the coherence point.
        double       s = 0.0;
        unsigned int c = 0u;
        #pragma unroll
        for (int j = 0; j < BLOCKS / TPB; ++j) {   // 8 partials per thread
            const unsigned long long v =
                __hip_atomic_load(&part[threadIdx.x + j * TPB],
                                  __ATOMIC_RELAXED, __HIP_MEMORY_SCOPE_AGENT);
            s += (double)__uint_as_float((unsigned int)(v & 0xffffffffull));
            c += (unsigned int)(v >> 32);
        }
        #pragma unroll
        for (int off = 32; off > 0; off >>= 1) {
            s += __shfl_down(s, off);
            c += __shfl_down(c, off);
        }
        __shared__ double       fs[4];
        __shared__ unsigned int fc[4];
        if (lane == 0) { fs[wave] = s; fc[wave] = c; }
        __syncthreads();
        if (threadIdx.x == 0) {
            const double       tot = fs[0] + fs[1] + fs[2] + fs[3];
            const unsigned int tc  = fc[0] + fc[1] + fc[2] + fc[3];
            out[0] = (float)((tot * (1.0 / (double)N_ELEM)) * (1.0 + 0.1 * (double)tc));
        }
    }
}

extern "C" void kernel_launch(void* const* d_in, const int* in_sizes, int n_in,
                              void* d_out, int out_size, void* d_ws, size_t ws_size,
                              hipStream_t stream) {
    const f4v* p4  = (const f4v*)d_in[0];
    const i4v* t4  = (const i4v*)d_in[1];
    float*     out = (float*)d_out;

    unsigned long long* part = (unsigned long long*)d_ws;
    unsigned int*       ctr  = (unsigned int*)((char*)d_ws + WS_CTR_OFF);

    // ticket must start at 0 every call (d_ws is poisoned 0xAA once after the
    // correctness call; nothing else re-inits it between timed replays).
    hipMemsetAsync(ctr, 0, sizeof(unsigned int), stream);

    cl_fused<<<BLOCKS, TPB, 0, stream>>>(p4, t4, part, ctr, out);
}

// Round 9
// 35.012 us; speedup vs baseline: 1.2648x; 1.2648x over previous
//
#include <hip/hip_runtime.h>

// N = 16,777,216 fp32 probabilities + int32 {0,1} targets.
//   count      = #{ p > 0.5 && t == 0 }
//   out        = mean( -(t*log p + (1-t)*log(1-p)) ) * (1 + 0.1*count)
//
// FINAL STRUCTURE (= R6, best measured 28.0 us):
// R1-R3: 79/65/62 us — plateau was f64 atomicAdd (CAS retry loop, 2048
//        blocks contending one address).
// R4:    disjoint partials + tiny 2nd kernel, no atomics: 30.9 us.
// R5:    fused ticket + __threadfence: 96 us — per-block device fence emits
//        buffer_wbl2 (whole-L2 writeback) x2048. Never fence per-block.
// R6:    + nontemporal loads (L2-bypass, no-reuse streams): 28.0 us.
//        Read phase ~22 us @ ~6.1 TB/s vs ~7.0 TB/s same-run fill-kernel
//        calibration and 21.3 us theoretical floor -> ~95% of achievable.
// R7:    float2-packed partials: 34.4 us — noise band is +/-3-6 us; run-level
//        calibration (fill kernels also slow) showed machine-state drift.
// R8:    fence-free fused ticket (sc1 atomics + vmcnt ordering): 44.3 us —
//        the per-replay 4-byte hipMemsetAsync node itself costs ~39 us as a
//        serialized graph fill dispatch. Both fusion routes dead; the split
//        2-kernel structure is optimal for this harness. Reverted to R6.

#define N_ELEM  16777216
#define N_VEC4  (N_ELEM / 4)       // 4,194,304
#define BLOCKS  2048
#define TPB     256
#define NTHREAD (BLOCKS * TPB)     // 524,288
#define NITER   (N_VEC4 / NTHREAD) // exactly 8

typedef float f4v __attribute__((ext_vector_type(4)));
typedef int   i4v __attribute__((ext_vector_type(4)));

// d_ws layout: [0 .. 16384) double psum[2048]; [16384 .. 24576) uint pcnt[2048]
#define WS_PCNT_OFF 16384

__global__ __launch_bounds__(TPB, 4) void cl_reduce(
    const f4v* __restrict__ p4,
    const i4v* __restrict__ t4,
    double*       __restrict__ psum,
    unsigned int* __restrict__ pcnt)
{
    const int tid = blockIdx.x * TPB + threadIdx.x;

    f4v p[NITER];
    i4v t[NITER];
    #pragma unroll
    for (int j = 0; j < NITER; ++j) {
        p[j] = __builtin_nontemporal_load(&p4[tid + j * NTHREAD]);
        t[j] = __builtin_nontemporal_load(&t4[tid + j * NTHREAD]);
    }
    __builtin_amdgcn_sched_barrier(0);

    float        lsum = 0.0f;
    unsigned int lcnt = 0u;
    #pragma unroll
    for (int j = 0; j < NITER; ++j) {
        lsum += __logf(t[j][0] ? p[j][0] : 1.0f - p[j][0]);
        lsum += __logf(t[j][1] ? p[j][1] : 1.0f - p[j][1]);
        lsum += __logf(t[j][2] ? p[j][2] : 1.0f - p[j][2]);
        lsum += __logf(t[j][3] ? p[j][3] : 1.0f - p[j][3]);
        lcnt += (unsigned int)((p[j][0] > 0.5f) & (t[j][0] == 0));
        lcnt += (unsigned int)((p[j][1] > 0.5f) & (t[j][1] == 0));
        lcnt += (unsigned int)((p[j][2] > 0.5f) & (t[j][2] == 0));
        lcnt += (unsigned int)((p[j][3] > 0.5f) & (t[j][3] == 0));
    }
    lsum = -lsum;

    // 64-lane wave reduction
    #pragma unroll
    for (int off = 32; off > 0; off >>= 1) {
        lsum += __shfl_down(lsum, off);
        lcnt += __shfl_down(lcnt, off);
    }

    // block reduction across 4 waves -> ONE disjoint store per block, no atomics
    __shared__ float        s_sum[4];
    __shared__ unsigned int s_cnt[4];
    const int wave = threadIdx.x >> 6;
    const int lane = threadIdx.x & 63;
    if (lane == 0) { s_sum[wave] = lsum; s_cnt[wave] = lcnt; }
    __syncthreads();
    if (threadIdx.x == 0) {
        psum[blockIdx.x] = (double)(s_sum[0] + s_sum[1] + s_sum[2] + s_sum[3]);
        pcnt[blockIdx.x] = s_cnt[0] + s_cnt[1] + s_cnt[2] + s_cnt[3];
    }
}

__global__ __launch_bounds__(TPB) void cl_final(
    const double*       __restrict__ psum,
    const unsigned int* __restrict__ pcnt,
    float*              __restrict__ out)
{
    double       s = 0.0;
    unsigned int c = 0u;
    #pragma unroll
    for (int j = 0; j < BLOCKS / TPB; ++j) {   // 8 partials per thread
        s += psum[threadIdx.x + j * TPB];
        c += pcnt[threadIdx.x + j * TPB];
    }
    #pragma unroll
    for (int off = 32; off > 0; off >>= 1) {
        s += __shfl_down(s, off);
        c += __shfl_down(c, off);
    }
    __shared__ double       ss[4];
    __shared__ unsigned int sc[4];
    const int wave = threadIdx.x >> 6;
    const int lane = threadIdx.x & 63;
    if (lane == 0) { ss[wave] = s; sc[wave] = c; }
    __syncthreads();
    if (threadIdx.x == 0) {
        const double       tot = ss[0] + ss[1] + ss[2] + ss[3];
        const unsigned int tc  = sc[0] + sc[1] + sc[2] + sc[3];
        out[0] = (float)((tot * (1.0 / (double)N_ELEM)) * (1.0 + 0.1 * (double)tc));
    }
}

extern "C" void kernel_launch(void* const* d_in, const int* in_sizes, int n_in,
                              void* d_out, int out_size, void* d_ws, size_t ws_size,
                              hipStream_t stream) {
    const f4v* p4  = (const f4v*)d_in[0];
    const i4v* t4  = (const i4v*)d_in[1];
    float*     out = (float*)d_out;

    double*       psum = (double*)d_ws;
    unsigned int* pcnt = (unsigned int*)((char*)d_ws + WS_PCNT_OFF);

    cl_reduce<<<BLOCKS, TPB, 0, stream>>>(p4, t4, psum, pcnt);
    cl_final<<<1, TPB, 0, stream>>>(psum, pcnt, out);
}